// Round 5
// baseline (648.785 us; speedup 1.0000x reference)
//
#include <hip/hip_runtime.h>
#include <cstdint>
#include <cstddef>

// Problem dims (fixed)
#define NN 131072      // nodes
#define EE 262144      // events
// msg GEMM: K = 448 = [mem_s 128 | mem_d 128 | raw 128 | tenc_s 32 | tenc_d 32], Nout = 256
// gru GEMM: K = 256 = [aggr 128 | memory 128], Nout = 512 = [r | z | i_n | h_n]

typedef __attribute__((ext_vector_type(8))) short bf16x8;
typedef __attribute__((ext_vector_type(4))) float f32x4;

__device__ __forceinline__ unsigned short f2bf(float f) {
    unsigned int u = __builtin_bit_cast(unsigned int, f);
    u += 0x7FFFu + ((u >> 16) & 1u);   // RNE
    return (unsigned short)(u >> 16);
}
__device__ __forceinline__ float bf2f(unsigned short s) {
    unsigned int u = ((unsigned int)s) << 16;
    return __builtin_bit_cast(float, u);
}
__device__ __forceinline__ float sigmoidf_(float x) { return 1.0f / (1.0f + __expf(-x)); }
__device__ __forceinline__ float tanhf_(float x) {
    float ax = fabsf(x);
    float e = __expf(-2.0f * ax);
    return copysignf((1.0f - e) / (1.0f + e), x);
}
__device__ __forceinline__ bf16x8 pack8(const float* f) {
    bf16x8 o;
#pragma unroll
    for (int i = 0; i < 8; ++i) o[i] = (short)f2bf(f[i]);
    return o;
}

// logical W' for the fused message GEMM (256 out x 448 in)
__device__ __forceinline__ float wmsg_val(int n, int k, const float* Ws, const float* Wd) {
    if (n < 128) {
        return (k < 416) ? Ws[n * 416 + k] : 0.0f;           // [mem_s, mem_d, raw, tenc_s]
    } else {
        int m = n - 128;
        if (k < 128)       return Wd[m * 416 + 128 + k];     // X' mem_s <- Wd block 1
        else if (k < 256)  return Wd[m * 416 + (k - 128)];   // X' mem_d <- Wd block 0
        else if (k < 384)  return Wd[m * 416 + k];           // raw
        else if (k < 416)  return 0.0f;                      // tenc_s unused by msg_d
        else               return Wd[m * 416 + 384 + (k - 416)]; // tenc_d
    }
}
// logical W for the GRU GEMM (512 out x 256 in)
__device__ __forceinline__ float wgru_val(int j, int k, const float* Wih, const float* Whh) {
    if (j < 256)      return (k < 128) ? Wih[j * 128 + k] : Whh[j * 128 + (k - 128)];
    else if (j < 384) return (k < 128) ? Wih[j * 128 + k] : 0.0f;
    else              return (k < 128) ? 0.0f : Whh[(j - 128) * 128 + (k - 128)];
}

// ---------------- prep: message weight in MFMA fragment order ----------------
// Wmf[((c*16 + nt)*64 + lane)*8 + j] ; c 0..13, nt 0..15
__global__ void k_prep_msgfrag(const float* __restrict__ Ws, const float* __restrict__ Wd,
                               const float* __restrict__ bs, const float* __restrict__ bd,
                               unsigned short* __restrict__ Wmf, float* __restrict__ bm) {
    int b = blockIdx.x;              // c*16 + nt
    int c = b >> 4, nt = b & 15;
    int lane = threadIdx.x;
    int col0 = lane & 15, q = lane >> 4;
    int n = nt * 16 + col0;
    float f[8];
#pragma unroll
    for (int j = 0; j < 8; ++j) f[j] = wmsg_val(n, c * 32 + q * 8 + j, Ws, Wd);
    ((bf16x8*)Wmf)[(size_t)b * 64 + lane] = pack8(f);
    if (b == 0)
        for (int i = lane; i < 256; i += 64) bm[i] = (i < 128) ? bs[i] : bd[i - 128];
}

// ---------------- prep: GRU weight in MFMA fragment order ----------------
// Wgf[((c*32 + nt)*64 + lane)*8 + j] ; c 0..7, nt 0..31
__global__ void k_prep_grufrag(const float* __restrict__ Wih, const float* __restrict__ Whh,
                               const float* __restrict__ bih, const float* __restrict__ bhh,
                               unsigned short* __restrict__ Wgf, float* __restrict__ bg) {
    int b = blockIdx.x;              // c*32 + nt
    int c = b >> 5, nt = b & 31;
    int lane = threadIdx.x;
    int col0 = lane & 15, q = lane >> 4;
    int j0 = nt * 16 + col0;
    float f[8];
#pragma unroll
    for (int j = 0; j < 8; ++j) f[j] = wgru_val(j0, c * 32 + q * 8 + j, Wih, Whh);
    ((bf16x8*)Wgf)[(size_t)b * 64 + lane] = pack8(f);
    if (b == 0)
        for (int i = lane; i < 512; i += 64)
            bg[i] = (i < 256) ? (bih[i] + bhh[i]) : ((i < 384) ? bih[i] : bhh[i - 128]);
}

// ---------------- memory fp32 -> bf16 table ----------------
__global__ void k_memconv(const float* __restrict__ in, unsigned short* __restrict__ outp) {
    int gid = blockIdx.x * 256 + threadIdx.x;
    const float4 v = ((const float4*)in)[gid];
    ushort4 o;
    o.x = f2bf(v.x); o.y = f2bf(v.y); o.z = f2bf(v.z); o.w = f2bf(v.w);
    *(ushort4*)(outp + (size_t)gid * 4) = o;
}

// ---------------- per-event: t_rel, counts, timestamp max ----------------
__global__ void k_pre(const int* __restrict__ t, const int* __restrict__ src,
                      const int* __restrict__ dst, const int* __restrict__ lu,
                      float* __restrict__ trel_s, float* __restrict__ trel_d,
                      int* cnt, int* lu_tmp) {
    int e = blockIdx.x * 256 + threadIdx.x;
    int s = src[e], d = dst[e], tv = t[e];
    trel_s[e] = (float)(tv - lu[s]);
    trel_d[e] = (float)(tv - lu[d]);
    atomicAdd(&cnt[s], 1);
    atomicAdd(&cnt[d], 1);
    atomicMax(&lu_tmp[s], tv);
    atomicMax(&lu_tmp[d], tv);
}

// ---------------- CSR scan: 3 stages ----------------
__global__ void k_scan1(const int* __restrict__ cnt, int* __restrict__ bsum) {
    __shared__ int red[256];
    int tid = threadIdx.x;
    red[tid] = cnt[blockIdx.x * 256 + tid];
    __syncthreads();
    for (int s = 128; s > 0; s >>= 1) {
        if (tid < s) red[tid] += red[tid + s];
        __syncthreads();
    }
    if (tid == 0) bsum[blockIdx.x] = red[0];
}
__global__ void k_scan2(const int* __restrict__ bsum, int* __restrict__ boff) {
    __shared__ int sb[512];
    int tid = threadIdx.x;
    int v = bsum[tid];
    sb[tid] = v;
    __syncthreads();
    for (int d = 1; d < 512; d <<= 1) {
        int u = (tid >= d) ? sb[tid - d] : 0;
        __syncthreads();
        sb[tid] += u;
        __syncthreads();
    }
    boff[tid] = sb[tid] - v;   // exclusive
}
__global__ void k_scan3(const int* __restrict__ cnt, const int* __restrict__ boff,
                        int* __restrict__ off, int* __restrict__ cursor) {
    __shared__ int sb[256];
    int tid = threadIdx.x;
    int i = blockIdx.x * 256 + tid;
    int v = cnt[i];
    sb[tid] = v;
    __syncthreads();
    for (int d = 1; d < 256; d <<= 1) {
        int u = (tid >= d) ? sb[tid - d] : 0;
        __syncthreads();
        sb[tid] += u;
        __syncthreads();
    }
    int o = boff[blockIdx.x] + sb[tid] - v;
    off[i] = o;
    cursor[i] = o;
}
// inverse permutation: event-side -> sorted position
__global__ void k_fill(const int* __restrict__ src, const int* __restrict__ dst,
                       int* cursor, int* __restrict__ pos2) {
    int e2 = blockIdx.x * 256 + threadIdx.x;   // [0,2E): <E = s-side, >=E = d-side
    int node = (e2 < EE) ? src[e2] : dst[e2 - EE];
    pos2[e2] = atomicAdd(&cursor[node], 1);
}

// ---------------- message GEMM -> msg_sorted[2E][128] bf16 ----------------
// 64 events x 256 outputs, K=448 in 14 chunks of 32. ZERO-STAGING structure:
// A-fragments are gathered/computed per-lane directly into registers (MFMA
// A-layout is K-contiguous: lane(col0,q) needs A[col0][q*8..q*8+8], and every
// A source — memb rows, raw rows, tenc(trel, tw-frag) — is K-contiguous in
// global). No LDS staging, no K-loop barriers: 12 fully-decoupled waves/CU,
// compiler free to pipeline gathers under MFMAs. A re-read x4 waves is
// L1/L2-absorbed (block working set ~64KB on one CU). acc[4][4] = 64 acc regs
// keeps 3 blocks/CU. Epilogue: per-wave LDS transpose -> 16B coalesced stores.
__launch_bounds__(256, 3)
__global__ void k_msg(const unsigned short* __restrict__ memb,
                      const float* __restrict__ raw,
                      const float* __restrict__ trel_s,
                      const float* __restrict__ trel_d,
                      const unsigned short* __restrict__ Wmf,
                      const float* __restrict__ bm,
                      const int* __restrict__ src, const int* __restrict__ dst,
                      const int* __restrict__ pos2,
                      const float* __restrict__ tw, const float* __restrict__ tb,
                      unsigned short* __restrict__ msg) {
    __shared__ int s_pos[64], d_pos[64];
    __shared__ __align__(16) unsigned short scr_all[4 * 1280];   // per-wave epilogue scratch

    const int tid = threadIdx.x;
    const int e0 = blockIdx.x * 64;
    if (tid < 64)        s_pos[tid] = pos2[e0 + tid];
    else if (tid < 128)  d_pos[tid - 64] = pos2[EE + e0 + tid - 64];

    const int lane = tid & 63, w = tid >> 6;
    const int col0 = lane & 15, q = lane >> 4;

    // per-lane event-row node ids (4 m-tiles; ev = mt*16 + col0)
    int sn[4], dn[4];
#pragma unroll
    for (int mt = 0; mt < 4; ++mt) {
        int ev = mt * 16 + col0;
        sn[mt] = src[e0 + ev];
        dn[mt] = dst[e0 + ev];
    }
    // per-lane time-encoder weight fragment (k = q*8 .. q*8+8), register-resident
    const float4 tw0 = *(const float4*)(tw + q * 8);
    const float4 tw1 = *(const float4*)(tw + q * 8 + 4);
    const float4 tb0 = *(const float4*)(tb + q * 8);
    const float4 tb1 = *(const float4*)(tb + q * 8 + 4);

    __syncthreads();   // s_pos/d_pos visible (only barrier in the kernel)

    f32x4 acc[4][4];
#pragma unroll
    for (int a = 0; a < 4; ++a)
#pragma unroll
        for (int b = 0; b < 4; ++b)
#pragma unroll
            for (int i = 0; i < 4; ++i) acc[a][b][i] = 0.0f;

#pragma unroll
    for (int c = 0; c < 14; ++c) {
        // B-fragments for this K=32 chunk (L2-resident prepacked weights)
        bf16x8 bfr[4];
        const bf16x8* Wc = (const bf16x8*)Wmf + (size_t)c * 16 * 64;
#pragma unroll
        for (int nl = 0; nl < 4; ++nl)
            bfr[nl] = Wc[(w * 4 + nl) * 64 + lane];

        // A-fragments built per-lane, straight from global / computed
        bf16x8 afr[4];
        if (c < 8) {
            // mem_s (c 0..3) / mem_d (c 4..7), k-cols (c&3)*32
            const int cb = (c & 3) * 32 + q * 8;
#pragma unroll
            for (int mt = 0; mt < 4; ++mt) {
                int node = (c < 4) ? sn[mt] : dn[mt];
                afr[mt] = *(const bf16x8*)(memb + (size_t)node * 128 + cb);
            }
        } else if (c < 12) {
            // raw fp32, k-cols (c-8)*32
            const int cb = (c - 8) * 32 + q * 8;
#pragma unroll
            for (int mt = 0; mt < 4; ++mt) {
                int ev = mt * 16 + col0;
                const float* rp = raw + (size_t)(e0 + ev) * 128 + cb;
                const float4 a = *(const float4*)rp;
                const float4 b = *(const float4*)(rp + 4);
                float f[8] = {a.x, a.y, a.z, a.w, b.x, b.y, b.z, b.w};
                afr[mt] = pack8(f);
            }
        } else {
            // time encodings: cos(trel * tw + tb), per-lane k-frag
            const float* trp = (c == 12) ? trel_s : trel_d;
#pragma unroll
            for (int mt = 0; mt < 4; ++mt) {
                int ev = mt * 16 + col0;
                float tr = trp[e0 + ev];
                float f[8];
                f[0] = __cosf(tr * tw0.x + tb0.x);
                f[1] = __cosf(tr * tw0.y + tb0.y);
                f[2] = __cosf(tr * tw0.z + tb0.z);
                f[3] = __cosf(tr * tw0.w + tb0.w);
                f[4] = __cosf(tr * tw1.x + tb1.x);
                f[5] = __cosf(tr * tw1.y + tb1.y);
                f[6] = __cosf(tr * tw1.z + tb1.z);
                f[7] = __cosf(tr * tw1.w + tb1.w);
                afr[mt] = pack8(f);
            }
        }

#pragma unroll
        for (int mt = 0; mt < 4; ++mt)
#pragma unroll
            for (int nl = 0; nl < 4; ++nl)
                acc[mt][nl] = __builtin_amdgcn_mfma_f32_16x16x32_bf16(afr[mt], bfr[nl], acc[mt][nl], 0, 0, 0);
    }

    // ---- epilogue: bias+relu, per-wave LDS transpose, 16B coalesced stores ----
    // per-wave scratch: 16 rows x 80 shorts (160B stride); row holds 8 granules
    // of 16B, granule-XOR-swizzled by row to break bank aliasing.
    unsigned short* scr = scr_all + w * 1280;
    const bool is_s = (w < 2);
#pragma unroll
    for (int mt = 0; mt < 4; ++mt) {
#pragma unroll
        for (int nl = 0; nl < 4; ++nl) {
            int j = (w * 4 + nl) * 16 + col0;
            float bv = bm[j];
            int gl = nl * 2 + (col0 >> 3);      // logical 16B granule within 64-col tile
            int ci = col0 & 7;                  // short index within granule
#pragma unroll
            for (int r = 0; r < 4; ++r) {
                int rr = q * 4 + r;             // row within 16-row tile
                float v = fmaxf(acc[mt][nl][r] + bv, 0.0f);
                scr[rr * 80 + ((gl + rr) & 7) * 8 + ci] = f2bf(v);
            }
        }
        // wave-local: DS ops are in-order per wave; just wait for writes to land
        asm volatile("s_waitcnt lgkmcnt(0)" ::: "memory");
        {
            int rr2 = lane & 15, p = lane >> 4;
            int ev = mt * 16 + rr2;
            int pos = is_s ? s_pos[ev] : d_pos[ev];
            bf16x8 v0 = *(const bf16x8*)&scr[rr2 * 80 + (((2 * p)     + rr2) & 7) * 8];
            bf16x8 v1 = *(const bf16x8*)&scr[rr2 * 80 + (((2 * p + 1) + rr2) & 7) * 8];
            unsigned short* dstp = msg + (size_t)pos * 128 + (w & 1) * 64 + p * 16;
            *(bf16x8*)dstp = v0;
            *(bf16x8*)(dstp + 8) = v1;
        }
        asm volatile("s_waitcnt lgkmcnt(0)" ::: "memory");
    }
}

// ---------------- fused mean-aggregation (sorted, contiguous) + GRU ----------------
// 64 nodes/block, 256 threads. Each per-chunk B-frag register set is reused by
// 4 m-tiles (was 2): halves the grid-wide Wgf L2 traffic (1 GB -> 512 MB) and
// doubles MFMA work per weight load. acc[4][4][2] = 128 acc regs -> (256,2).
__launch_bounds__(256, 2)
__global__ void k_gru(const unsigned short* __restrict__ msg,
                      const int* __restrict__ off, const int* __restrict__ cnt,
                      const float* __restrict__ memory,
                      const unsigned short* __restrict__ Wgf,
                      const float* __restrict__ bg,
                      float* __restrict__ out) {
    __shared__ __align__(16) unsigned short Xs[64 * 264];

    const int tid = threadIdx.x;
    const int n0 = blockIdx.x * 64;

    // aggregation: 8 threads/node, 16 feats each; two 32-node passes
#pragma unroll
    for (int h = 0; h < 2; ++h) {
        int g = tid >> 3, sub = tid & 7;
        int gr = h * 32 + g;
        int node = n0 + gr;
        int beg = off[node], cn = cnt[node];
        float a[16];
#pragma unroll
        for (int i = 0; i < 16; ++i) a[i] = 0.0f;
        for (int m = 0; m < cn; ++m) {
            const bf16x8* p = (const bf16x8*)(msg + (size_t)(beg + m) * 128 + sub * 16);
            bf16x8 v0 = p[0], v1 = p[1];
#pragma unroll
            for (int k = 0; k < 8; ++k) {
                a[k]     += bf2f((unsigned short)v0[k]);
                a[8 + k] += bf2f((unsigned short)v1[k]);
            }
        }
        float inv = 1.0f / (float)(cn > 1 ? cn : 1);
#pragma unroll
        for (int i = 0; i < 16; ++i) a[i] *= inv;
        *(bf16x8*)&Xs[gr * 264 + sub * 16] = pack8(&a[0]);
        *(bf16x8*)&Xs[gr * 264 + sub * 16 + 8] = pack8(&a[8]);
        // memory half
        float f[16];
        const float4* mp = (const float4*)(memory + (size_t)node * 128 + sub * 16);
#pragma unroll
        for (int s = 0; s < 4; ++s) {
            float4 v = mp[s];
            f[s * 4 + 0] = v.x; f[s * 4 + 1] = v.y; f[s * 4 + 2] = v.z; f[s * 4 + 3] = v.w;
        }
        *(bf16x8*)&Xs[gr * 264 + 128 + sub * 16] = pack8(&f[0]);
        *(bf16x8*)&Xs[gr * 264 + 128 + sub * 16 + 8] = pack8(&f[8]);
    }
    __syncthreads();

    const int lane = tid & 63, w = tid >> 6;
    const int col0 = lane & 15, q = lane >> 4;

    f32x4 acc[4][4][2];   // [mt][gate][fh]
#pragma unroll
    for (int a = 0; a < 4; ++a)
#pragma unroll
        for (int g = 0; g < 4; ++g)
#pragma unroll
            for (int f = 0; f < 2; ++f)
#pragma unroll
                for (int i = 0; i < 4; ++i) acc[a][g][f][i] = 0.0f;

#pragma unroll
    for (int c = 0; c < 8; ++c) {
        bf16x8 bfr[4][2];
        const bf16x8* Wc = (const bf16x8*)Wgf + (size_t)c * 32 * 64;
#pragma unroll
        for (int g = 0; g < 4; ++g)
#pragma unroll
            for (int fh = 0; fh < 2; ++fh)
                bfr[g][fh] = Wc[(8 * g + 2 * w + fh) * 64 + lane];
        bf16x8 afr[4];
#pragma unroll
        for (int mt = 0; mt < 4; ++mt)
            afr[mt] = *(const bf16x8*)&Xs[(mt * 16 + col0) * 264 + c * 32 + q * 8];
#pragma unroll
        for (int mt = 0; mt < 4; ++mt)
#pragma unroll
            for (int g = 0; g < 4; ++g)
#pragma unroll
                for (int fh = 0; fh < 2; ++fh)
                    acc[mt][g][fh] = __builtin_amdgcn_mfma_f32_16x16x32_bf16(afr[mt], bfr[g][fh], acc[mt][g][fh], 0, 0, 0);
    }

    // epilogue: gates + blend
#pragma unroll
    for (int fh = 0; fh < 2; ++fh) {
        int feat = w * 32 + fh * 16 + col0;
        float b_r = bg[feat], b_z = bg[128 + feat], b_in = bg[256 + feat], b_hn = bg[384 + feat];
#pragma unroll
        for (int mt = 0; mt < 4; ++mt) {
#pragma unroll
            for (int r = 0; r < 4; ++r) {
                int node = n0 + mt * 16 + q * 4 + r;
                float rr = sigmoidf_(acc[mt][0][fh][r] + b_r);
                float zz = sigmoidf_(acc[mt][1][fh][r] + b_z);
                float nn = tanhf_((acc[mt][2][fh][r] + b_in) + rr * (acc[mt][3][fh][r] + b_hn));
                float h = memory[(size_t)node * 128 + feat];
                out[(size_t)node * 128 + feat] = (1.0f - zz) * nn + zz * h;
            }
        }
    }
}

// ---------------- last_update -> float output ----------------
__global__ void k_lu(const int* __restrict__ lu_tmp, float* __restrict__ outp) {
    int i = blockIdx.x * 256 + threadIdx.x;
    outp[i] = (float)lu_tmp[i];
}

extern "C" void kernel_launch(void* const* d_in, const int* in_sizes, int n_in,
                              void* d_out, int out_size, void* d_ws, size_t ws_size,
                              hipStream_t stream) {
    const float* memory = (const float*)d_in[0];
    const float* raw    = (const float*)d_in[1];
    const float* tw     = (const float*)d_in[2];
    const float* tb     = (const float*)d_in[3];
    const float* Wms    = (const float*)d_in[4];
    const float* bms    = (const float*)d_in[5];
    const float* Wmd    = (const float*)d_in[6];
    const float* bmd    = (const float*)d_in[7];
    const float* Wih    = (const float*)d_in[8];
    const float* Whh    = (const float*)d_in[9];
    const float* bih    = (const float*)d_in[10];
    const float* bhh    = (const float*)d_in[11];
    const int* src = (const int*)d_in[12];
    const int* dst = (const int*)d_in[13];
    const int* t   = (const int*)d_in[14];
    const int* lu  = (const int*)d_in[15];

    char* ws = (char*)d_ws;
    size_t ob = 0;
    unsigned short* memb = (unsigned short*)(ws + ob); ob += (size_t)NN * 128 * 2;       // 32 MB
    unsigned short* msg  = (unsigned short*)(ws + ob); ob += (size_t)2 * EE * 128 * 2;   // 128 MB (sorted)
    float* trel_s        = (float*)(ws + ob);          ob += (size_t)EE * 4;
    float* trel_d        = (float*)(ws + ob);          ob += (size_t)EE * 4;
    int* cnt             = (int*)(ws + ob);            ob += (size_t)NN * 4;
    int* off             = (int*)(ws + ob);            ob += (size_t)NN * 4;
    int* cursor          = (int*)(ws + ob);            ob += (size_t)NN * 4;
    int* lu_tmp          = (int*)(ws + ob);            ob += (size_t)NN * 4;
    int* pos2            = (int*)(ws + ob);            ob += (size_t)2 * EE * 4;         // 2 MB
    int* bsum            = (int*)(ws + ob);            ob += 512 * 4;
    int* boff            = (int*)(ws + ob);            ob += 512 * 4;
    unsigned short* Wmf  = (unsigned short*)(ws + ob); ob += (size_t)14 * 16 * 64 * 8 * 2;
    float* bm            = (float*)(ws + ob);          ob += 256 * 4;
    unsigned short* Wgf  = (unsigned short*)(ws + ob); ob += (size_t)8 * 32 * 64 * 8 * 2;
    float* bg            = (float*)(ws + ob);          ob += 512 * 4;

    float* out = (float*)d_out;

    hipMemsetAsync(cnt, 0, (size_t)NN * 4, stream);
    hipMemsetAsync(lu_tmp, 0, (size_t)NN * 4, stream);

    k_prep_msgfrag<<<14 * 16, 64, 0, stream>>>(Wms, Wmd, bms, bmd, Wmf, bm);
    k_prep_grufrag<<<8 * 32, 64, 0, stream>>>(Wih, Whh, bih, bhh, Wgf, bg);
    k_memconv<<<(NN * 128 / 4) / 256, 256, 0, stream>>>(memory, memb);
    k_pre<<<EE / 256, 256, 0, stream>>>(t, src, dst, lu, trel_s, trel_d, cnt, lu_tmp);
    k_scan1<<<512, 256, 0, stream>>>(cnt, bsum);
    k_scan2<<<1, 512, 0, stream>>>(bsum, boff);
    k_scan3<<<512, 256, 0, stream>>>(cnt, boff, off, cursor);
    k_fill<<<2 * EE / 256, 256, 0, stream>>>(src, dst, cursor, pos2);
    k_msg<<<EE / 64, 256, 0, stream>>>(memb, raw, trel_s, trel_d, Wmf, bm, src, dst, pos2, tw, tb, msg);
    k_gru<<<NN / 64, 256, 0, stream>>>(msg, off, cnt, memory, Wgf, bg, out);
    k_lu<<<NN / 256, 256, 0, stream>>>(lu_tmp, out + (size_t)NN * 128);
}

// Round 6
// 547.577 us; speedup vs baseline: 1.1848x; 1.1848x over previous
//
#include <hip/hip_runtime.h>
#include <cstdint>
#include <cstddef>

// Problem dims (fixed)
#define NN 131072      // nodes
#define EE 262144      // events
// msg GEMM: K = 448 = [mem_s 128 | mem_d 128 | raw 128 | tenc_s 32 | tenc_d 32], Nout = 256
// gru GEMM: K = 256 = [aggr 128 | memory 128], Nout = 512 = [r | z | i_n | h_n]

typedef __attribute__((ext_vector_type(8))) short bf16x8;
typedef __attribute__((ext_vector_type(4))) float f32x4;

__device__ __forceinline__ unsigned short f2bf(float f) {
    unsigned int u = __builtin_bit_cast(unsigned int, f);
    u += 0x7FFFu + ((u >> 16) & 1u);   // RNE
    return (unsigned short)(u >> 16);
}
__device__ __forceinline__ float bf2f(unsigned short s) {
    unsigned int u = ((unsigned int)s) << 16;
    return __builtin_bit_cast(float, u);
}
__device__ __forceinline__ float sigmoidf_(float x) { return 1.0f / (1.0f + __expf(-x)); }
__device__ __forceinline__ float tanhf_(float x) {
    float ax = fabsf(x);
    float e = __expf(-2.0f * ax);
    return copysignf((1.0f - e) / (1.0f + e), x);
}
__device__ __forceinline__ bf16x8 pack8(const float* f) {
    bf16x8 o;
#pragma unroll
    for (int i = 0; i < 8; ++i) o[i] = (short)f2bf(f[i]);
    return o;
}

// logical W' for the fused message GEMM (256 out x 448 in)
__device__ __forceinline__ float wmsg_val(int n, int k, const float* Ws, const float* Wd) {
    if (n < 128) {
        return (k < 416) ? Ws[n * 416 + k] : 0.0f;           // [mem_s, mem_d, raw, tenc_s]
    } else {
        int m = n - 128;
        if (k < 128)       return Wd[m * 416 + 128 + k];     // X' mem_s <- Wd block 1
        else if (k < 256)  return Wd[m * 416 + (k - 128)];   // X' mem_d <- Wd block 0
        else if (k < 384)  return Wd[m * 416 + k];           // raw
        else if (k < 416)  return 0.0f;                      // tenc_s unused by msg_d
        else               return Wd[m * 416 + 384 + (k - 416)]; // tenc_d
    }
}
// logical W for the GRU GEMM (512 out x 256 in)
__device__ __forceinline__ float wgru_val(int j, int k, const float* Wih, const float* Whh) {
    if (j < 256)      return (k < 128) ? Wih[j * 128 + k] : Whh[j * 128 + (k - 128)];
    else if (j < 384) return (k < 128) ? Wih[j * 128 + k] : 0.0f;
    else              return (k < 128) ? 0.0f : Whh[(j - 128) * 128 + (k - 128)];
}

// ---------------- prep: message weight in MFMA fragment order ----------------
// Wmf[((c*16 + nt)*64 + lane)*8 + j] ; c 0..13, nt 0..15
__global__ void k_prep_msgfrag(const float* __restrict__ Ws, const float* __restrict__ Wd,
                               const float* __restrict__ bs, const float* __restrict__ bd,
                               unsigned short* __restrict__ Wmf, float* __restrict__ bm) {
    int b = blockIdx.x;              // c*16 + nt
    int c = b >> 4, nt = b & 15;
    int lane = threadIdx.x;
    int col0 = lane & 15, q = lane >> 4;
    int n = nt * 16 + col0;
    float f[8];
#pragma unroll
    for (int j = 0; j < 8; ++j) f[j] = wmsg_val(n, c * 32 + q * 8 + j, Ws, Wd);
    ((bf16x8*)Wmf)[(size_t)b * 64 + lane] = pack8(f);
    if (b == 0)
        for (int i = lane; i < 256; i += 64) bm[i] = (i < 128) ? bs[i] : bd[i - 128];
}

// ---------------- prep: GRU weight in MFMA fragment order ----------------
// Wgf[((c*32 + nt)*64 + lane)*8 + j] ; c 0..7, nt 0..31
__global__ void k_prep_grufrag(const float* __restrict__ Wih, const float* __restrict__ Whh,
                               const float* __restrict__ bih, const float* __restrict__ bhh,
                               unsigned short* __restrict__ Wgf, float* __restrict__ bg) {
    int b = blockIdx.x;              // c*32 + nt
    int c = b >> 5, nt = b & 31;
    int lane = threadIdx.x;
    int col0 = lane & 15, q = lane >> 4;
    int j0 = nt * 16 + col0;
    float f[8];
#pragma unroll
    for (int j = 0; j < 8; ++j) f[j] = wgru_val(j0, c * 32 + q * 8 + j, Wih, Whh);
    ((bf16x8*)Wgf)[(size_t)b * 64 + lane] = pack8(f);
    if (b == 0)
        for (int i = lane; i < 512; i += 64)
            bg[i] = (i < 256) ? (bih[i] + bhh[i]) : ((i < 384) ? bih[i] : bhh[i - 128]);
}

// ---------------- memory fp32 -> bf16 table ----------------
__global__ void k_memconv(const float* __restrict__ in, unsigned short* __restrict__ outp) {
    int gid = blockIdx.x * 256 + threadIdx.x;
    const float4 v = ((const float4*)in)[gid];
    ushort4 o;
    o.x = f2bf(v.x); o.y = f2bf(v.y); o.z = f2bf(v.z); o.w = f2bf(v.w);
    *(ushort4*)(outp + (size_t)gid * 4) = o;
}

// ---------------- per-event: t_rel, counts, timestamp max ----------------
__global__ void k_pre(const int* __restrict__ t, const int* __restrict__ src,
                      const int* __restrict__ dst, const int* __restrict__ lu,
                      float* __restrict__ trel_s, float* __restrict__ trel_d,
                      int* cnt, int* lu_tmp) {
    int e = blockIdx.x * 256 + threadIdx.x;
    int s = src[e], d = dst[e], tv = t[e];
    trel_s[e] = (float)(tv - lu[s]);
    trel_d[e] = (float)(tv - lu[d]);
    atomicAdd(&cnt[s], 1);
    atomicAdd(&cnt[d], 1);
    atomicMax(&lu_tmp[s], tv);
    atomicMax(&lu_tmp[d], tv);
}

// ---------------- CSR scan: 3 stages ----------------
__global__ void k_scan1(const int* __restrict__ cnt, int* __restrict__ bsum) {
    __shared__ int red[256];
    int tid = threadIdx.x;
    red[tid] = cnt[blockIdx.x * 256 + tid];
    __syncthreads();
    for (int s = 128; s > 0; s >>= 1) {
        if (tid < s) red[tid] += red[tid + s];
        __syncthreads();
    }
    if (tid == 0) bsum[blockIdx.x] = red[0];
}
__global__ void k_scan2(const int* __restrict__ bsum, int* __restrict__ boff) {
    __shared__ int sb[512];
    int tid = threadIdx.x;
    int v = bsum[tid];
    sb[tid] = v;
    __syncthreads();
    for (int d = 1; d < 512; d <<= 1) {
        int u = (tid >= d) ? sb[tid - d] : 0;
        __syncthreads();
        sb[tid] += u;
        __syncthreads();
    }
    boff[tid] = sb[tid] - v;   // exclusive
}
__global__ void k_scan3(const int* __restrict__ cnt, const int* __restrict__ boff,
                        int* __restrict__ off, int* __restrict__ cursor) {
    __shared__ int sb[256];
    int tid = threadIdx.x;
    int i = blockIdx.x * 256 + tid;
    int v = cnt[i];
    sb[tid] = v;
    __syncthreads();
    for (int d = 1; d < 256; d <<= 1) {
        int u = (tid >= d) ? sb[tid - d] : 0;
        __syncthreads();
        sb[tid] += u;
        __syncthreads();
    }
    int o = boff[blockIdx.x] + sb[tid] - v;
    off[i] = o;
    cursor[i] = o;
}
// inverse permutation: event-side -> sorted position
__global__ void k_fill(const int* __restrict__ src, const int* __restrict__ dst,
                       int* cursor, int* __restrict__ pos2) {
    int e2 = blockIdx.x * 256 + threadIdx.x;   // [0,2E): <E = s-side, >=E = d-side
    int node = (e2 < EE) ? src[e2] : dst[e2 - EE];
    pos2[e2] = atomicAdd(&cursor[node], 1);
}

// ---------------- message GEMM -> msg_sorted[2E][128] bf16 ----------------
// 64 events x 256 outputs. K=448 in FOUR natural super-chunks:
//   SC0 = mem_s (K=128), SC1 = mem_d (K=128), SC2 = raw (K=128), SC3 = tenc (K=64)
// Main-loop barriers: 4 (was 7 at K=64, 14 at K=32; measured dur fits
// 103us + 4.1us x n_barriers). 64/56 MFMAs per wave per barrier interval.
// Coalesced LDS staging (8-16 lanes per row), double-buffered, 2-deep register
// prefetch (T14). lgkm-only barriers keep gathers in flight (proven neutral r4,
// theoretically better). acc[4][4] = 64 acc regs -> 3 blocks/CU. Epilogue:
// per-wave LDS transpose -> 16B coalesced stores (WRITE_SIZE ideal since r1).
__launch_bounds__(256, 3)
__global__ void k_msg(const unsigned short* __restrict__ memb,
                      const float* __restrict__ raw,
                      const float* __restrict__ trel_s,
                      const float* __restrict__ trel_d,
                      const unsigned short* __restrict__ Wmf,
                      const float* __restrict__ bm,
                      const int* __restrict__ src, const int* __restrict__ dst,
                      const int* __restrict__ pos2,
                      const float* __restrict__ tw, const float* __restrict__ tb,
                      unsigned short* __restrict__ msg) {
    __shared__ int s_idx[64], d_idx[64], s_pos[64], d_pos[64];
    __shared__ float s_tw[32], s_tb[32];
    __shared__ __align__(16) unsigned short As[2][64 * 136];   // 64 rows x 128 cols, +8 pad

    const int tid = threadIdx.x;
    const int e0 = blockIdx.x * 64;
    if (tid < 64)        { s_idx[tid] = src[e0 + tid];            s_pos[tid] = pos2[e0 + tid]; }
    else if (tid < 128)  { d_idx[tid - 64] = dst[e0 + tid - 64];  d_pos[tid - 64] = pos2[EE + e0 + tid - 64]; }
    else if (tid < 160)  s_tw[tid - 128] = tw[tid - 128];
    else if (tid < 192)  s_tb[tid - 160] = tb[tid - 160];
    __syncthreads();

    const int lane = tid & 63, w = tid >> 6;
    const int col0 = lane & 15, q = lane >> 4;

    // staging decompositions (coalesced: 16-32 consecutive lanes per row)
    const int mrow = tid >> 4, mseg = tid & 15;   // memb: 4 passes, rows +16/pass, 16 segs x 16B
    const int rrow = tid >> 5, rseg = tid & 31;   // raw:  8 passes, rows +8/pass, 32 segs x 16B
    const int trow = tid >> 2, tq   = tid & 3;    // tenc: 16 cos per thread

    // prefetch registers (explicitly named -> stay in VGPRs, rule #20)
    float4 p0, p1, p2, p3, p4, p5, p6, p7;

    auto stage_load = [&](int t) {
        if (t < 2) {                 // memb rows (s or d), full 128 cols
            const int* idx = (t == 0) ? s_idx : d_idx;
            p0 = *(const float4*)(memb + (size_t)idx[mrow +  0] * 128 + mseg * 8);
            p1 = *(const float4*)(memb + (size_t)idx[mrow + 16] * 128 + mseg * 8);
            p2 = *(const float4*)(memb + (size_t)idx[mrow + 32] * 128 + mseg * 8);
            p3 = *(const float4*)(memb + (size_t)idx[mrow + 48] * 128 + mseg * 8);
        } else if (t == 2) {         // raw fp32, full 128 cols
            const float* rbase = raw + (size_t)e0 * 128 + rseg * 4;
            p0 = *(const float4*)(rbase + (size_t)(rrow +  0) * 128);
            p1 = *(const float4*)(rbase + (size_t)(rrow +  8) * 128);
            p2 = *(const float4*)(rbase + (size_t)(rrow + 16) * 128);
            p3 = *(const float4*)(rbase + (size_t)(rrow + 24) * 128);
            p4 = *(const float4*)(rbase + (size_t)(rrow + 32) * 128);
            p5 = *(const float4*)(rbase + (size_t)(rrow + 40) * 128);
            p6 = *(const float4*)(rbase + (size_t)(rrow + 48) * 128);
            p7 = *(const float4*)(rbase + (size_t)(rrow + 56) * 128);
        } else {                     // tenc: load trel only
            p0.x = (tq < 2) ? trel_s[e0 + trow] : trel_d[e0 + trow];
        }
    };

    auto stage_write = [&](int t, unsigned short* A) {
        if (t < 2) {
            *(bf16x8*)&A[(mrow +  0) * 136 + mseg * 8] = __builtin_bit_cast(bf16x8, p0);
            *(bf16x8*)&A[(mrow + 16) * 136 + mseg * 8] = __builtin_bit_cast(bf16x8, p1);
            *(bf16x8*)&A[(mrow + 32) * 136 + mseg * 8] = __builtin_bit_cast(bf16x8, p2);
            *(bf16x8*)&A[(mrow + 48) * 136 + mseg * 8] = __builtin_bit_cast(bf16x8, p3);
        } else if (t == 2) {
            ushort4 o;
            o.x = f2bf(p0.x); o.y = f2bf(p0.y); o.z = f2bf(p0.z); o.w = f2bf(p0.w);
            *(ushort4*)&A[(rrow +  0) * 136 + rseg * 4] = o;
            o.x = f2bf(p1.x); o.y = f2bf(p1.y); o.z = f2bf(p1.z); o.w = f2bf(p1.w);
            *(ushort4*)&A[(rrow +  8) * 136 + rseg * 4] = o;
            o.x = f2bf(p2.x); o.y = f2bf(p2.y); o.z = f2bf(p2.z); o.w = f2bf(p2.w);
            *(ushort4*)&A[(rrow + 16) * 136 + rseg * 4] = o;
            o.x = f2bf(p3.x); o.y = f2bf(p3.y); o.z = f2bf(p3.z); o.w = f2bf(p3.w);
            *(ushort4*)&A[(rrow + 24) * 136 + rseg * 4] = o;
            o.x = f2bf(p4.x); o.y = f2bf(p4.y); o.z = f2bf(p4.z); o.w = f2bf(p4.w);
            *(ushort4*)&A[(rrow + 32) * 136 + rseg * 4] = o;
            o.x = f2bf(p5.x); o.y = f2bf(p5.y); o.z = f2bf(p5.z); o.w = f2bf(p5.w);
            *(ushort4*)&A[(rrow + 40) * 136 + rseg * 4] = o;
            o.x = f2bf(p6.x); o.y = f2bf(p6.y); o.z = f2bf(p6.z); o.w = f2bf(p6.w);
            *(ushort4*)&A[(rrow + 48) * 136 + rseg * 4] = o;
            o.x = f2bf(p7.x); o.y = f2bf(p7.y); o.z = f2bf(p7.z); o.w = f2bf(p7.w);
            *(ushort4*)&A[(rrow + 56) * 136 + rseg * 4] = o;
        } else {
            // SC3 cols 0-31 = cos(trel_s*tw+tb), cols 32-63 = cos(trel_d*tw+tb)
            float f[16];
            float tr = p0.x;
#pragma unroll
            for (int j = 0; j < 16; ++j) {
                int jj = (tq & 1) * 16 + j;
                f[j] = __cosf(tr * s_tw[jj] + s_tb[jj]);
            }
            *(bf16x8*)&A[trow * 136 + tq * 16]     = pack8(&f[0]);
            *(bf16x8*)&A[trow * 136 + tq * 16 + 8] = pack8(&f[8]);
        }
    };

    f32x4 acc[4][4];
#pragma unroll
    for (int a = 0; a < 4; ++a)
#pragma unroll
        for (int b = 0; b < 4; ++b)
#pragma unroll
            for (int i = 0; i < 4; ++i) acc[a][b][i] = 0.0f;

    // prologue: fill LDS[0] with SC0, leave SC1 in flight in regs.
    stage_load(0);
    stage_write(0, As[0]);
    stage_load(1);
    asm volatile("s_waitcnt lgkmcnt(0)" ::: "memory");
    __builtin_amdgcn_s_barrier();

#pragma unroll
    for (int t = 0; t < 4; ++t) {
        const unsigned short* A = As[t & 1];
        // write SC t+1 (regs loaded 1 interval ago) into the alternate buffer
        if (t < 3) stage_write(t + 1, As[(t + 1) & 1]);
        // issue SC t+2's global loads (~2 full intervals of latency budget)
        if (t < 2) stage_load(t + 2);
        const int nkk = (t == 3) ? 2 : 4;
#pragma unroll
        for (int kk = 0; kk < 4; ++kk) {
            if (kk >= nkk) break;
            const int c = (t < 3) ? (t * 4 + kk) : (12 + kk);
            bf16x8 bfr[4];
            const bf16x8* Wc = (const bf16x8*)Wmf + (size_t)c * 16 * 64;
#pragma unroll
            for (int nl = 0; nl < 4; ++nl)
                bfr[nl] = Wc[(w * 4 + nl) * 64 + lane];
            bf16x8 afr[4];
#pragma unroll
            for (int mt = 0; mt < 4; ++mt)
                afr[mt] = *(const bf16x8*)&A[(mt * 16 + col0) * 136 + kk * 32 + q * 8];
#pragma unroll
            for (int mt = 0; mt < 4; ++mt)
#pragma unroll
                for (int nl = 0; nl < 4; ++nl)
                    acc[mt][nl] = __builtin_amdgcn_mfma_f32_16x16x32_bf16(afr[mt], bfr[nl], acc[mt][nl], 0, 0, 0);
        }
        // lgkm-only drain + raw barrier: producer LDS writes visible, global
        // gathers (stage_load t+2) stay in flight across the barrier.
        asm volatile("s_waitcnt lgkmcnt(0)" ::: "memory");
        __builtin_amdgcn_s_barrier();
    }

    // ---- epilogue: bias+relu, per-wave LDS transpose (reuse As), 16B stores ----
    // per-wave scratch: 16 rows x 80 shorts (160B stride, 16B aligned); row holds
    // 8 granules of 16B, granule-XOR-swizzled by row to break bank aliasing.
    unsigned short* scr = &As[0][0] + w * 1280;
    const bool is_s = (w < 2);
#pragma unroll
    for (int mt = 0; mt < 4; ++mt) {
#pragma unroll
        for (int nl = 0; nl < 4; ++nl) {
            int j = (w * 4 + nl) * 16 + col0;
            float bv = bm[j];
            int gl = nl * 2 + (col0 >> 3);      // logical 16B granule within 64-col tile
            int ci = col0 & 7;                  // short index within granule
#pragma unroll
            for (int r = 0; r < 4; ++r) {
                int rr = q * 4 + r;             // row within 16-row tile
                float v = fmaxf(acc[mt][nl][r] + bv, 0.0f);
                scr[rr * 80 + ((gl + rr) & 7) * 8 + ci] = f2bf(v);
            }
        }
        // wave-local: DS ops are in-order per wave; just wait for writes to land
        asm volatile("s_waitcnt lgkmcnt(0)" ::: "memory");
        {
            int rr2 = lane & 15, p = lane >> 4;
            int ev = mt * 16 + rr2;
            int pos = is_s ? s_pos[ev] : d_pos[ev];
            bf16x8 v0 = *(const bf16x8*)&scr[rr2 * 80 + (((2 * p)     + rr2) & 7) * 8];
            bf16x8 v1 = *(const bf16x8*)&scr[rr2 * 80 + (((2 * p + 1) + rr2) & 7) * 8];
            unsigned short* dstp = msg + (size_t)pos * 128 + (w & 1) * 64 + p * 16;
            *(bf16x8*)dstp = v0;
            *(bf16x8*)(dstp + 8) = v1;
        }
        asm volatile("s_waitcnt lgkmcnt(0)" ::: "memory");
    }
}

// ---------------- fused mean-aggregation (sorted, contiguous) + GRU ----------------
// 64 nodes/block, 256 threads. Each per-chunk B-frag register set is reused by
// 4 m-tiles: halves the grid-wide Wgf L2 traffic and doubles MFMA work per
// weight load. acc[4][4][2] = 128 acc regs -> (256,2).
__launch_bounds__(256, 2)
__global__ void k_gru(const unsigned short* __restrict__ msg,
                      const int* __restrict__ off, const int* __restrict__ cnt,
                      const float* __restrict__ memory,
                      const unsigned short* __restrict__ Wgf,
                      const float* __restrict__ bg,
                      float* __restrict__ out) {
    __shared__ __align__(16) unsigned short Xs[64 * 264];

    const int tid = threadIdx.x;
    const int n0 = blockIdx.x * 64;

    // aggregation: 8 threads/node, 16 feats each; two 32-node passes
#pragma unroll
    for (int h = 0; h < 2; ++h) {
        int g = tid >> 3, sub = tid & 7;
        int gr = h * 32 + g;
        int node = n0 + gr;
        int beg = off[node], cn = cnt[node];
        float a[16];
#pragma unroll
        for (int i = 0; i < 16; ++i) a[i] = 0.0f;
        for (int m = 0; m < cn; ++m) {
            const bf16x8* p = (const bf16x8*)(msg + (size_t)(beg + m) * 128 + sub * 16);
            bf16x8 v0 = p[0], v1 = p[1];
#pragma unroll
            for (int k = 0; k < 8; ++k) {
                a[k]     += bf2f((unsigned short)v0[k]);
                a[8 + k] += bf2f((unsigned short)v1[k]);
            }
        }
        float inv = 1.0f / (float)(cn > 1 ? cn : 1);
#pragma unroll
        for (int i = 0; i < 16; ++i) a[i] *= inv;
        *(bf16x8*)&Xs[gr * 264 + sub * 16] = pack8(&a[0]);
        *(bf16x8*)&Xs[gr * 264 + sub * 16 + 8] = pack8(&a[8]);
        // memory half
        float f[16];
        const float4* mp = (const float4*)(memory + (size_t)node * 128 + sub * 16);
#pragma unroll
        for (int s = 0; s < 4; ++s) {
            float4 v = mp[s];
            f[s * 4 + 0] = v.x; f[s * 4 + 1] = v.y; f[s * 4 + 2] = v.z; f[s * 4 + 3] = v.w;
        }
        *(bf16x8*)&Xs[gr * 264 + 128 + sub * 16] = pack8(&f[0]);
        *(bf16x8*)&Xs[gr * 264 + 128 + sub * 16 + 8] = pack8(&f[8]);
    }
    __syncthreads();

    const int lane = tid & 63, w = tid >> 6;
    const int col0 = lane & 15, q = lane >> 4;

    f32x4 acc[4][4][2];   // [mt][gate][fh]
#pragma unroll
    for (int a = 0; a < 4; ++a)
#pragma unroll
        for (int g = 0; g < 4; ++g)
#pragma unroll
            for (int f = 0; f < 2; ++f)
#pragma unroll
                for (int i = 0; i < 4; ++i) acc[a][g][f][i] = 0.0f;

#pragma unroll
    for (int c = 0; c < 8; ++c) {
        bf16x8 bfr[4][2];
        const bf16x8* Wc = (const bf16x8*)Wgf + (size_t)c * 32 * 64;
#pragma unroll
        for (int g = 0; g < 4; ++g)
#pragma unroll
            for (int fh = 0; fh < 2; ++fh)
                bfr[g][fh] = Wc[(8 * g + 2 * w + fh) * 64 + lane];
        bf16x8 afr[4];
#pragma unroll
        for (int mt = 0; mt < 4; ++mt)
            afr[mt] = *(const bf16x8*)&Xs[(mt * 16 + col0) * 264 + c * 32 + q * 8];
#pragma unroll
        for (int mt = 0; mt < 4; ++mt)
#pragma unroll
            for (int g = 0; g < 4; ++g)
#pragma unroll
                for (int fh = 0; fh < 2; ++fh)
                    acc[mt][g][fh] = __builtin_amdgcn_mfma_f32_16x16x32_bf16(afr[mt], bfr[g][fh], acc[mt][g][fh], 0, 0, 0);
    }

    // epilogue: gates + blend
#pragma unroll
    for (int fh = 0; fh < 2; ++fh) {
        int feat = w * 32 + fh * 16 + col0;
        float b_r = bg[feat], b_z = bg[128 + feat], b_in = bg[256 + feat], b_hn = bg[384 + feat];
#pragma unroll
        for (int mt = 0; mt < 4; ++mt) {
#pragma unroll
            for (int r = 0; r < 4; ++r) {
                int node = n0 + mt * 16 + q * 4 + r;
                float rr = sigmoidf_(acc[mt][0][fh][r] + b_r);
                float zz = sigmoidf_(acc[mt][1][fh][r] + b_z);
                float nn = tanhf_((acc[mt][2][fh][r] + b_in) + rr * (acc[mt][3][fh][r] + b_hn));
                float h = memory[(size_t)node * 128 + feat];
                out[(size_t)node * 128 + feat] = (1.0f - zz) * nn + zz * h;
            }
        }
    }
}

// ---------------- last_update -> float output ----------------
__global__ void k_lu(const int* __restrict__ lu_tmp, float* __restrict__ outp) {
    int i = blockIdx.x * 256 + threadIdx.x;
    outp[i] = (float)lu_tmp[i];
}

extern "C" void kernel_launch(void* const* d_in, const int* in_sizes, int n_in,
                              void* d_out, int out_size, void* d_ws, size_t ws_size,
                              hipStream_t stream) {
    const float* memory = (const float*)d_in[0];
    const float* raw    = (const float*)d_in[1];
    const float* tw     = (const float*)d_in[2];
    const float* tb     = (const float*)d_in[3];
    const float* Wms    = (const float*)d_in[4];
    const float* bms    = (const float*)d_in[5];
    const float* Wmd    = (const float*)d_in[6];
    const float* bmd    = (const float*)d_in[7];
    const float* Wih    = (const float*)d_in[8];
    const float* Whh    = (const float*)d_in[9];
    const float* bih    = (const float*)d_in[10];
    const float* bhh    = (const float*)d_in[11];
    const int* src = (const int*)d_in[12];
    const int* dst = (const int*)d_in[13];
    const int* t   = (const int*)d_in[14];
    const int* lu  = (const int*)d_in[15];

    char* ws = (char*)d_ws;
    size_t ob = 0;
    unsigned short* memb = (unsigned short*)(ws + ob); ob += (size_t)NN * 128 * 2;       // 32 MB
    unsigned short* msg  = (unsigned short*)(ws + ob); ob += (size_t)2 * EE * 128 * 2;   // 128 MB (sorted)
    float* trel_s        = (float*)(ws + ob);          ob += (size_t)EE * 4;
    float* trel_d        = (float*)(ws + ob);          ob += (size_t)EE * 4;
    int* cnt             = (int*)(ws + ob);            ob += (size_t)NN * 4;
    int* off             = (int*)(ws + ob);            ob += (size_t)NN * 4;
    int* cursor          = (int*)(ws + ob);            ob += (size_t)NN * 4;
    int* lu_tmp          = (int*)(ws + ob);            ob += (size_t)NN * 4;
    int* pos2            = (int*)(ws + ob);            ob += (size_t)2 * EE * 4;         // 2 MB
    int* bsum            = (int*)(ws + ob);            ob += 512 * 4;
    int* boff            = (int*)(ws + ob);            ob += 512 * 4;
    unsigned short* Wmf  = (unsigned short*)(ws + ob); ob += (size_t)14 * 16 * 64 * 8 * 2;
    float* bm            = (float*)(ws + ob);          ob += 256 * 4;
    unsigned short* Wgf  = (unsigned short*)(ws + ob); ob += (size_t)8 * 32 * 64 * 8 * 2;
    float* bg            = (float*)(ws + ob);          ob += 512 * 4;

    float* out = (float*)d_out;

    hipMemsetAsync(cnt, 0, (size_t)NN * 4, stream);
    hipMemsetAsync(lu_tmp, 0, (size_t)NN * 4, stream);

    k_prep_msgfrag<<<14 * 16, 64, 0, stream>>>(Wms, Wmd, bms, bmd, Wmf, bm);
    k_prep_grufrag<<<8 * 32, 64, 0, stream>>>(Wih, Whh, bih, bhh, Wgf, bg);
    k_memconv<<<(NN * 128 / 4) / 256, 256, 0, stream>>>(memory, memb);
    k_pre<<<EE / 256, 256, 0, stream>>>(t, src, dst, lu, trel_s, trel_d, cnt, lu_tmp);
    k_scan1<<<512, 256, 0, stream>>>(cnt, bsum);
    k_scan2<<<1, 512, 0, stream>>>(bsum, boff);
    k_scan3<<<512, 256, 0, stream>>>(cnt, boff, off, cursor);
    k_fill<<<2 * EE / 256, 256, 0, stream>>>(src, dst, cursor, pos2);
    k_msg<<<EE / 64, 256, 0, stream>>>(memb, raw, trel_s, trel_d, Wmf, bm, src, dst, pos2, tw, tb, msg);
    k_gru<<<NN / 64, 256, 0, stream>>>(msg, off, cnt, memory, Wgf, bg, out);
    k_lu<<<NN / 256, 256, 0, stream>>>(lu_tmp, out + (size_t)NN * 128);
}